// Round 4
// baseline (738.937 us; speedup 1.0000x reference)
//
#include <hip/hip_runtime.h>
#include <cstddef>

static constexpr int   NN      = 2048;
static constexpr int   TPB_B   = 256;   // build_cost block
static constexpr int   TPB     = 1024;  // main kernel block (16 waves)
static constexpr int   NWB     = TPB / 64;          // 16 waves/block
static constexpr int   NB      = 128;               // main grid blocks
static constexpr int   MAX_IT  = 100;
static constexpr float EPS     = 0.1f;
static constexpr float INV_EPS = 10.0f;
// logf(1/2048 + 1e-8)
static constexpr float LOG_AB  = -7.6245985063594f;
static constexpr float THRESH  = 0.1f;

#define ALOAD(p)     __hip_atomic_load((p),  __ATOMIC_RELAXED, __HIP_MEMORY_SCOPE_AGENT)
#define ASTORE(p, x) __hip_atomic_store((p), (x), __ATOMIC_RELAXED, __HIP_MEMORY_SCOPE_AGENT)

typedef unsigned long long u64;
typedef unsigned int u32x4 __attribute__((ext_vector_type(4)));

// 16B coherent poll load: one transaction instead of two 8B atomics.
// sc0 sc1 = system-scope bypass (>= agent): always reads past the XCD L2,
// same coherence point the 8B agent atomics used. Layout of the 16B:
// [val0][ep0][val1][ep1] (two {epoch<<32|f32} u64 entries, little-endian).
__device__ __forceinline__ u32x4 poll16(const u64* p)
{
    u32x4 q;
    asm volatile("global_load_dwordx4 %0, %1, off sc0 sc1\n\t"
                 "s_waitcnt vmcnt(0)"
                 : "=v"(q) : "v"(p) : "memory");
    return q;
}

__device__ __forceinline__ void post16(const u64* p, u32x4 s)
{
    asm volatile("global_store_dwordx4 %0, %1, off sc0 sc1"
                 :: "v"(p), "v"(s) : "memory");
}

// ---------------------------------------------------------------------------
// Cost matrix build + signal-region zeroing. C[i][j] = sum_d (x[i,d]-y[j,d])^2.
// (harness poisons ws with 0xAA before every call -> re-zero signals every
//  launch; kernel-end L2 writeback makes plain stores visible to bypass loads)
// ---------------------------------------------------------------------------
__global__ __launch_bounds__(TPB_B)
void build_cost(const float* __restrict__ x, const float* __restrict__ y,
                float* __restrict__ C, float* __restrict__ CT,
                unsigned* __restrict__ zz, int zcount,
                int c_aligned, int use_ct)
{
    __shared__ float xs[64][65];
    __shared__ float ys[64][65];
    const int t  = threadIdx.x;
    const int bi = blockIdx.y, bj = blockIdx.x;

    if (bi == 0) {                       // 32 blocks zero the region in parallel
        int per = (zcount + 31) / 32;
        int lo = bj * per;
        int hi = lo + per; if (hi > zcount) hi = zcount;
        for (int idx = lo + t; idx < hi; idx += TPB_B) zz[idx] = 0u;
    }

#pragma unroll
    for (int k = 0; k < 16; ++k) {
        int idx = t + TPB_B * k;
        int r = idx >> 6, c = idx & 63;
        xs[r][c] = x[(size_t)(bi * 64 + r) * 64 + c];
        ys[r][c] = y[(size_t)(bj * 64 + r) * 64 + c];
    }
    __syncthreads();

    const int ti0 = (t >> 4) * 4;
    const int tj0 = (t & 15) * 4;
    float acc[4][4] = {};
#pragma unroll 8
    for (int d = 0; d < 64; ++d) {
        float xv[4], yv[4];
#pragma unroll
        for (int k = 0; k < 4; ++k) xv[k] = xs[ti0 + k][d];
#pragma unroll
        for (int l = 0; l < 4; ++l) yv[l] = ys[tj0 + l][d];
#pragma unroll
        for (int k = 0; k < 4; ++k)
#pragma unroll
            for (int l = 0; l < 4; ++l) {
                float df = xv[k] - yv[l];
                acc[k][l] = fmaf(df, df, acc[k][l]);
            }
    }

#pragma unroll
    for (int k = 0; k < 4; ++k) {
        size_t off = (size_t)(bi * 64 + ti0 + k) * NN + bj * 64 + tj0;
        if (c_aligned) {
            *(float4*)(C + off) = make_float4(acc[k][0], acc[k][1], acc[k][2], acc[k][3]);
        } else {
            C[off + 0] = acc[k][0]; C[off + 1] = acc[k][1];
            C[off + 2] = acc[k][2]; C[off + 3] = acc[k][3];
        }
    }
    if (use_ct) {
#pragma unroll
        for (int l = 0; l < 4; ++l) {
            size_t off = (size_t)(bj * 64 + tj0 + l) * NN + bi * 64 + ti0;
            *(float4*)(CT + off) = make_float4(acc[0][l], acc[1][l], acc[2][l], acc[3][l]);
        }
    }
}

// ---------------------------------------------------------------------------
// Helpers
// ---------------------------------------------------------------------------
__device__ __forceinline__ void load_row32(const float* row, int lane,
                                           int aligned, float c[32])
{
    if (aligned) {
        const float4* r4 = (const float4*)row;
#pragma unroll
        for (int k = 0; k < 8; ++k) {
            float4 A = r4[lane + 64 * k];
            c[4*k+0] = A.x; c[4*k+1] = A.y; c[4*k+2] = A.z; c[4*k+3] = A.w;
        }
    } else {
#pragma unroll
        for (int k = 0; k < 8; ++k) {
            const float* p = row + 4 * (lane + 64 * k);
            c[4*k+0] = p[0]; c[4*k+1] = p[1]; c[4*k+2] = p[2]; c[4*k+3] = p[3];
        }
    }
}

__device__ __forceinline__ void lds_row32(const float* sv, int lane, float b[32])
{
    const float4* s4 = (const float4*)sv;
#pragma unroll
    for (int k = 0; k < 8; ++k) {
        float4 A = s4[lane + 64 * k];
        b[4*k+0] = A.x; b[4*k+1] = A.y; b[4*k+2] = A.z; b[4*k+3] = A.w;
    }
}

// wave-level lse of (b-c)*INV_EPS over 2048 elems; result on ALL lanes.
__device__ __forceinline__ float wave_lse(const float c[32], const float b[32])
{
    float M = b[0] - c[0];
#pragma unroll
    for (int k = 1; k < 32; ++k) M = fmaxf(M, b[k] - c[k]);
#pragma unroll
    for (int off = 1; off < 64; off <<= 1) M = fmaxf(M, __shfl_xor(M, off));
    float Ms = M * INV_EPS;
    float s = 0.0f;
#pragma unroll
    for (int k = 0; k < 32; ++k) s += __expf(fmaf(b[k] - c[k], INV_EPS, -Ms));
#pragma unroll
    for (int off = 1; off < 64; off <<= 1) s += __shfl_xor(s, off);
    return Ms + __logf(s);
}

// ---------------------------------------------------------------------------
// Main cooperative kernel — the proven structure with the conv-check FUSED
// into the poll-A spin (4 barriers/iter instead of 6):
//   * threads t<NB issue the two (always-warm) rot loads INSIDE their valA
//     spin rounds; exit requires valA fresh AND rot fresh. Deadlock-free:
//     any block that posts A(ep) already posted rotC(ep-1) in program order,
//     so when valA(ep) is fully visible rot(ep-1) is posted (at worst one
//     extra visibility round). No serial pre-spin (the R2 mistake).
//   * reduce lands in sred4 before the existing post-poll-A barrier; break
//     check is a barrier-free read of sred4[0]+sred4[1] (identical value,
//     identical order in every block -> uniform break iteration).
//   * break state bit-identical to the proven kernel: u_keep committed only
//     after the check (so u_keep=u(it)); sv restored to v(it) from per-
//     thread registers vo0/vo1 saved at poll-B.
// Everything else unchanged: staged coalesced 16B posts, self-validating
// {epoch|f32} entries, detection IS the fetch, no fences.
// Cm may alias out+1 (crow/ccol register-resident before any overwrite).
// ---------------------------------------------------------------------------
__global__ __launch_bounds__(TPB)
void sinkhorn_main(const float* Cm, const float* __restrict__ CT,
                   u64* __restrict__ valA, u64* __restrict__ valB,
                   u64* __restrict__ rotR, u64* __restrict__ rotC,
                   u64* __restrict__ costb,
                   float* out, int c_aligned, int use_ct)
{
    __shared__ float sv[2048];
    __shared__ float swave[NWB];
    __shared__ float sdw[NWB];
    __shared__ float sred4[4];
    const int t = threadIdx.x, lane = t & 63, w = t >> 6, b = blockIdx.x;
    const int i = b * NWB + w;

    // loop-invariant C row / CT col -> registers
    float crow[32], ccol[32];
    load_row32(Cm + (size_t)i * NN, lane, c_aligned, crow);
    if (use_ct) {
        load_row32(CT + (size_t)i * NN, lane, 1, ccol);
    } else {
#pragma unroll
        for (int k = 0; k < 8; ++k)
#pragma unroll
            for (int kk = 0; kk < 4; ++kk)
                ccol[4*k+kk] = Cm[(size_t)(4 * (lane + 64 * k) + kk) * NN + i];
    }

    for (int k = t; k < 2048; k += TPB) sv[k] = 0.0f;   // v(0) = 0
    __syncthreads();

    float u_keep = 0.0f, v_keep = 0.0f;
    float vo0 = 0.0f, vo1 = 0.0f;        // v(it) copies for break restore
    float b32[32];

    for (int it = 0; it < MAX_IT; ++it) {
        const unsigned ep = (unsigned)(it + 1);

        // ---- row compute: u(ep)_i from sv = v(it)
        lds_row32(sv, lane, b32);
        float lse   = wave_lse(crow, b32);
        float u_new = EPS * (LOG_AB - lse);          // wave-uniform
        float pdr   = fabsf(u_new - u_keep);         // |u(ep)-u(it)|

        // ---- post A(ep): staged values (8x 16B wave-store) + block pdiff
        if (lane == 0) { swave[w] = u_new; sdw[w] = pdr; }
        __syncthreads();                                            // S1
        if (t < NWB / 2) {
            u32x4 s;
            s.x = __float_as_uint(swave[2*t + 0]); s.y = ep;
            s.z = __float_as_uint(swave[2*t + 1]); s.w = ep;
            post16(&valA[b * NWB + 2*t], s);
        }
        if (t == 0) {
            float ps = 0.0f;
#pragma unroll
            for (int k = 0; k < NWB; ++k) ps += sdw[k];
            ASTORE(&rotR[(ep & 3) * NB + b],
                   ((u64)ep << 32) | __float_as_uint(ps));
        }

        // ---- poll A -> sv = u(ep); conv-inputs of epoch `it` (warm) ride
        //      the same spin rounds for threads t<NB
        {
            const bool needrot = (it >= 1) & (t < NB);
            const int  ri = (it & 3) * NB + t;
            u32x4 q; u64 r1 = 0, r2 = 0;
            bool rotok = !needrot;
            for (;;) {
                q = poll16(&valA[2 * t]);
                if (!rotok) {
                    r1 = ALOAD(&rotR[ri]);
                    r2 = ALOAD(&rotC[ri]);
                    rotok = ((unsigned)(r1 >> 32) >= (unsigned)it) &
                            ((unsigned)(r2 >> 32) >= (unsigned)it);
                }
                if (((q.y >= ep) & (q.w >= ep)) & rotok) break;
            }
            ((float2*)sv)[t] = make_float2(__uint_as_float(q.x),
                                           __uint_as_float(q.z));
            if (needrot) {
                float d = __uint_as_float((unsigned)r1) +
                          __uint_as_float((unsigned)r2);
#pragma unroll
                for (int off = 1; off < 64; off <<= 1) d += __shfl_xor(d, off);
                if (lane == 0) sred4[w] = d;
            }
        }
        __syncthreads();                                            // S2

        // ---- deferred convergence check of iteration `it` (barrier-free)
        if (it >= 1) {
            float sd = sred4[0] + sred4[1];          // uniform across blocks
            if (sd < THRESH) {
                // restore sv = v(it); frozen state u_keep=u(it), sv=v(it)
                ((float2*)sv)[t] = make_float2(vo0, vo1);
                __syncthreads();
                break;
            }
        }
        u_keep = u_new;

        // ---- col compute: v(ep)_j from sv = u(ep)
        lds_row32(sv, lane, b32);
        lse = wave_lse(ccol, b32);
        float v_new = EPS * (LOG_AB - lse);
        float pdc   = fabsf(v_new - v_keep);
        v_keep = v_new;

        if (lane == 0) { swave[w] = v_new; sdw[w] = pdc; }
        __syncthreads();                                            // S3
        if (t < NWB / 2) {
            u32x4 s;
            s.x = __float_as_uint(swave[2*t + 0]); s.y = ep;
            s.z = __float_as_uint(swave[2*t + 1]); s.w = ep;
            post16(&valB[b * NWB + 2*t], s);
        }
        if (t == 0) {
            float ps = 0.0f;
#pragma unroll
            for (int k = 0; k < NWB; ++k) ps += sdw[k];
            ASTORE(&rotC[(ep & 3) * NB + b],
                   ((u64)ep << 32) | __float_as_uint(ps));
        }
        // ---- poll B -> sv = v(ep); keep own copies for break restore
        {
            u32x4 q;
            for (;;) {
                q = poll16(&valB[2 * t]);
                if ((q.y >= ep) & (q.w >= ep)) break;
            }
            float f0 = __uint_as_float(q.x);
            float f1 = __uint_as_float(q.z);
            ((float2*)sv)[t] = make_float2(f0, f1);
            vo0 = f0; vo1 = f1;
        }
        __syncthreads();                                            // S4
    }

    // ---- epilogue: pi = exp((u_i + v_j - C_ij)/eps), cost = sum(pi*C)
    float cpart = 0.0f;
    {
        lds_row32(sv, lane, b32);          // sv = final v
        const float ui = u_keep;           // own row's final u (wave-uniform)
        float* orow = out + 1 + (size_t)i * NN;
#pragma unroll
        for (int k = 0; k < 8; ++k) {
#pragma unroll
            for (int kk = 0; kk < 4; ++kk) {
                float cc = crow[4*k+kk];
                float p  = __expf((ui + b32[4*k+kk] - cc) * INV_EPS);
                cpart = fmaf(p, cc, cpart);
                orow[4 * (lane + 64 * k) + kk] = p;  // crow in regs: alias-safe
            }
        }
    }
#pragma unroll
    for (int off = 1; off < 64; off <<= 1) cpart += __shfl_xor(cpart, off);
    if (lane == 0) sdw[w] = cpart;
    __syncthreads();
    if (t == 0) {
        float pc = 0.0f;
#pragma unroll
        for (int k = 0; k < NWB; ++k) pc += sdw[k];
        ASTORE(&costb[b], (1ull << 32) | __float_as_uint(pc));
    }
    if (b == 0) {                          // block 0 gathers the cost total
        if (t < NB) {
            u64 h;
            for (;;) { h = ALOAD(&costb[t]); if (h >= (1ull << 32)) break; }
            float pc = __uint_as_float((unsigned)h);
#pragma unroll
            for (int off = 1; off < 64; off <<= 1) pc += __shfl_xor(pc, off);
            if (lane == 0) sred4[w] = pc;
        }
        __syncthreads();
        if (t == 0) out[0] = sred4[0] + sred4[1];
    }
}

// ---------------------------------------------------------------------------
extern "C" void kernel_launch(void* const* d_in, const int* in_sizes, int n_in,
                              void* d_out, int out_size, void* d_ws, size_t ws_size,
                              hipStream_t stream)
{
    (void)in_sizes; (void)n_in; (void)out_size;
    const float* x = (const float*)d_in[0];
    const float* y = (const float*)d_in[1];
    float* out = (float*)d_out;
    char*  ws  = (char*)d_ws;

    const size_t CB = (size_t)NN * NN * sizeof(float);   // 16 MiB
    // signals: valA(2048) valB(2048) rotR(4*128) rotC(4*128) costb(128) u64
    const int    ZU = 2048 + 2048 + 512 + 512 + 128;     // 5248 u64
    const size_t ZB = (size_t)ZU * sizeof(u64);

    float *Cm, *CT; char* zz;
    int c_aligned, use_ct;
    if (ws_size >= 2 * CB + ZB) {             // preferred: C, CT, signals in ws
        Cm = (float*)ws; CT = (float*)(ws + CB); zz = ws + 2 * CB;
        c_aligned = 1; use_ct = 1;
    } else if (ws_size >= CB + ZB) {          // C in out+1, CT in ws
        Cm = out + 1; CT = (float*)ws; zz = ws + CB;
        c_aligned = 0; use_ct = 1;
    } else {                                  // C in out+1, no CT (strided)
        Cm = out + 1; CT = nullptr; zz = ws;
        c_aligned = 0; use_ct = 0;
    }
    u64* valA  = (u64*)zz;
    u64* valB  = valA + 2048;
    u64* rotR  = valB + 2048;
    u64* rotC  = rotR + 512;
    u64* costb = rotC + 512;
    int  zcount = ZU * 2;                     // u32 elements to zero

    hipLaunchKernelGGL(build_cost, dim3(32, 32), dim3(TPB_B), 0, stream,
                       x, y, Cm, CT, (unsigned*)zz, zcount, c_aligned, use_ct);

    const float* Cmc = Cm;
    const float* CTc = CT;
    void* args[] = { (void*)&Cmc, (void*)&CTc, (void*)&valA, (void*)&valB,
                     (void*)&rotR, (void*)&rotC, (void*)&costb,
                     (void*)&out, (void*)&c_aligned, (void*)&use_ct };
    hipLaunchCooperativeKernel((void*)sinkhorn_main, dim3(NB), dim3(TPB),
                               args, 0, stream);
}

// Round 6
// 737.564 us; speedup vs baseline: 1.0019x; 1.0019x over previous
//
#include <hip/hip_runtime.h>
#include <cstddef>

static constexpr int   NN      = 2048;
static constexpr int   TPB_B   = 256;   // build_cost block
static constexpr int   TPB     = 1024;  // main kernel block (16 waves)
static constexpr int   NWB     = TPB / 64;          // 16 waves/block
static constexpr int   NB      = 128;               // main grid blocks
static constexpr int   MAX_IT  = 100;
static constexpr float EPS     = 0.1f;
static constexpr float INV_EPS = 10.0f;
// logf(1/2048 + 1e-8)
static constexpr float LOG_AB  = -7.6245985063594f;
static constexpr float THRESH  = 0.1f;

#define ALOAD(p)     __hip_atomic_load((p),  __ATOMIC_RELAXED, __HIP_MEMORY_SCOPE_AGENT)
#define ASTORE(p, x) __hip_atomic_store((p), (x), __ATOMIC_RELAXED, __HIP_MEMORY_SCOPE_AGENT)

typedef unsigned long long u64;
typedef unsigned int u32x4 __attribute__((ext_vector_type(4)));

// ---------------------------------------------------------------------------
// 16B coherent poll load: one transaction, load+wait+use in ONE asm block
// (R5 lesson: splitting load and waitcnt across asm blocks lets the compiler
// retarget registers -> poison reads that PASS the epoch check). sc0 sc1 =
// bypass the non-coherent per-XCD L2; reads/writes at the IC coherence
// point, same as agent-scope atomics. Layout: [val0][ep0][val1][ep1].
// ---------------------------------------------------------------------------
__device__ __forceinline__ u32x4 poll16(const u64* p)
{
    u32x4 q;
    asm volatile("global_load_dwordx4 %0, %1, off sc0 sc1\n\t"
                 "s_waitcnt vmcnt(0)"
                 : "=v"(q) : "v"(p) : "memory");
    return q;
}

__device__ __forceinline__ void post16(const u64* p, u32x4 s)
{
    asm volatile("global_store_dwordx4 %0, %1, off sc0 sc1"
                 :: "v"(p), "v"(s) : "memory");
}

// ---------------------------------------------------------------------------
// Cost matrix build + signal-region zeroing. C[i][j] = sum_d (x[i,d]-y[j,d])^2.
// (harness poisons ws with 0xAA before every call -> re-zero signals every
//  launch; kernel-end L2 writeback makes plain stores visible to bypass loads)
// ---------------------------------------------------------------------------
__global__ __launch_bounds__(TPB_B)
void build_cost(const float* __restrict__ x, const float* __restrict__ y,
                float* __restrict__ C, float* __restrict__ CT,
                unsigned* __restrict__ zz, int zcount,
                int c_aligned, int use_ct)
{
    __shared__ float xs[64][65];
    __shared__ float ys[64][65];
    const int t  = threadIdx.x;
    const int bi = blockIdx.y, bj = blockIdx.x;

    if (bi == 0) {                       // 32 blocks zero the region in parallel
        int per = (zcount + 31) / 32;
        int lo = bj * per;
        int hi = lo + per; if (hi > zcount) hi = zcount;
        for (int idx = lo + t; idx < hi; idx += TPB_B) zz[idx] = 0u;
    }

#pragma unroll
    for (int k = 0; k < 16; ++k) {
        int idx = t + TPB_B * k;
        int r = idx >> 6, c = idx & 63;
        xs[r][c] = x[(size_t)(bi * 64 + r) * 64 + c];
        ys[r][c] = y[(size_t)(bj * 64 + r) * 64 + c];
    }
    __syncthreads();

    const int ti0 = (t >> 4) * 4;
    const int tj0 = (t & 15) * 4;
    float acc[4][4] = {};
#pragma unroll 8
    for (int d = 0; d < 64; ++d) {
        float xv[4], yv[4];
#pragma unroll
        for (int k = 0; k < 4; ++k) xv[k] = xs[ti0 + k][d];
#pragma unroll
        for (int l = 0; l < 4; ++l) yv[l] = ys[tj0 + l][d];
#pragma unroll
        for (int k = 0; k < 4; ++k)
#pragma unroll
            for (int l = 0; l < 4; ++l) {
                float df = xv[k] - yv[l];
                acc[k][l] = fmaf(df, df, acc[k][l]);
            }
    }

#pragma unroll
    for (int k = 0; k < 4; ++k) {
        size_t off = (size_t)(bi * 64 + ti0 + k) * NN + bj * 64 + tj0;
        if (c_aligned) {
            *(float4*)(C + off) = make_float4(acc[k][0], acc[k][1], acc[k][2], acc[k][3]);
        } else {
            C[off + 0] = acc[k][0]; C[off + 1] = acc[k][1];
            C[off + 2] = acc[k][2]; C[off + 3] = acc[k][3];
        }
    }
    if (use_ct) {
#pragma unroll
        for (int l = 0; l < 4; ++l) {
            size_t off = (size_t)(bj * 64 + tj0 + l) * NN + bi * 64 + ti0;
            *(float4*)(CT + off) = make_float4(acc[0][l], acc[1][l], acc[2][l], acc[3][l]);
        }
    }
}

// ---------------------------------------------------------------------------
// Helpers
// ---------------------------------------------------------------------------
__device__ __forceinline__ void load_row32(const float* row, int lane,
                                           int aligned, float c[32])
{
    if (aligned) {
        const float4* r4 = (const float4*)row;
#pragma unroll
        for (int k = 0; k < 8; ++k) {
            float4 A = r4[lane + 64 * k];
            c[4*k+0] = A.x; c[4*k+1] = A.y; c[4*k+2] = A.z; c[4*k+3] = A.w;
        }
    } else {
#pragma unroll
        for (int k = 0; k < 8; ++k) {
            const float* p = row + 4 * (lane + 64 * k);
            c[4*k+0] = p[0]; c[4*k+1] = p[1]; c[4*k+2] = p[2]; c[4*k+3] = p[3];
        }
    }
}

__device__ __forceinline__ void lds_row32(const float* sv, int lane, float b[32])
{
    const float4* s4 = (const float4*)sv;
#pragma unroll
    for (int k = 0; k < 8; ++k) {
        float4 A = s4[lane + 64 * k];
        b[4*k+0] = A.x; b[4*k+1] = A.y; b[4*k+2] = A.z; b[4*k+3] = A.w;
    }
}

// wave-level lse of (b-c)*INV_EPS over 2048 elems; result on ALL lanes.
__device__ __forceinline__ float wave_lse(const float c[32], const float b[32])
{
    float M = b[0] - c[0];
#pragma unroll
    for (int k = 1; k < 32; ++k) M = fmaxf(M, b[k] - c[k]);
#pragma unroll
    for (int off = 1; off < 64; off <<= 1) M = fmaxf(M, __shfl_xor(M, off));
    float Ms = M * INV_EPS;
    float s = 0.0f;
#pragma unroll
    for (int k = 0; k < 32; ++k) s += __expf(fmaf(b[k] - c[k], INV_EPS, -Ms));
#pragma unroll
    for (int off = 1; off < 64; off <<= 1) s += __shfl_xor(s, off);
    return Ms + __logf(s);
}

// ---------------------------------------------------------------------------
// Main cooperative kernel — R3 (644us) with the conv-check FOLDED into the
// existing staging barrier (6 -> 4 barriers/iter), exact semantics:
//   * reorder: row-compute -> stage (lane0 -> swave/sdw) -> conv spin
//     (t<NB, warm: rotR(it) posted ~5us ago, rotC(it) ~2.5us ago) -> S1.
//     ONE barrier now covers staging AND sred4.
//   * every thread computes sd = sred4[0]+sred4[1] itself (identical value,
//     identical order in all blocks -> uniform break; no t0/sdiff serialize).
//   * break sits BEFORE post-A: frozen state u_keep=u(it), sv=v(it) is
//     bit-identical to R3's break state. Epoch ep is never posted on break.
// LDS hazard audit: sred4/swave/sdw written pre-S1, read just after S1 by
// waves 0-1 (post/rot threads); their next writes are pre-S3, which is
// unreachable until S2, and S2 requires the post threads to have finished
// their reads -> no race. Everything else identical to R3: staged 16B
// posts, self-validating {epoch|f32} entries, detection IS the fetch,
// load+waitcnt fused in one asm block, no fences.
// Cm may alias out+1 (crow/ccol register-resident before any overwrite).
// ---------------------------------------------------------------------------
__global__ __launch_bounds__(TPB)
void sinkhorn_main(const float* Cm, const float* __restrict__ CT,
                   u64* __restrict__ valA, u64* __restrict__ valB,
                   u64* __restrict__ rotR, u64* __restrict__ rotC,
                   u64* __restrict__ costb,
                   float* out, int c_aligned, int use_ct)
{
    __shared__ float sv[2048];
    __shared__ float swave[NWB];
    __shared__ float sdw[NWB];
    __shared__ float sred4[4];
    const int t = threadIdx.x, lane = t & 63, w = t >> 6, b = blockIdx.x;
    const int i = b * NWB + w;

    // loop-invariant C row / CT col -> registers
    float crow[32], ccol[32];
    load_row32(Cm + (size_t)i * NN, lane, c_aligned, crow);
    if (use_ct) {
        load_row32(CT + (size_t)i * NN, lane, 1, ccol);
    } else {
#pragma unroll
        for (int k = 0; k < 8; ++k)
#pragma unroll
            for (int kk = 0; kk < 4; ++kk)
                ccol[4*k+kk] = Cm[(size_t)(4 * (lane + 64 * k) + kk) * NN + i];
    }

    for (int k = t; k < 2048; k += TPB) sv[k] = 0.0f;   // v(0) = 0
    __syncthreads();

    float u_keep = 0.0f, v_keep = 0.0f;
    float b32[32];

    for (int it = 0; it < MAX_IT; ++it) {
        const unsigned ep = (unsigned)(it + 1);

        // ---- row compute: u(ep)_i from sv = v(it)
        lds_row32(sv, lane, b32);
        float lse   = wave_lse(crow, b32);
        float u_new = EPS * (LOG_AB - lse);          // wave-uniform
        float pdr   = fabsf(u_new - u_keep);

        // ---- stage u(ep) + pdiff for the posts (read after S1)
        if (lane == 0) { swave[w] = u_new; sdw[w] = pdr; }

        // ---- conv inputs of iteration `it` (always-warm; posted >=2.5us
        //      ago) gathered by waves 0-1 while others head to S1
        if (it >= 1 && t < NB) {
            u64 r1, r2;
            const int ri = (it & 3) * NB + t;
            for (;;) {
                r1 = ALOAD(&rotR[ri]);
                r2 = ALOAD(&rotC[ri]);
                if (((unsigned)(r1 >> 32) >= (unsigned)it) &
                    ((unsigned)(r2 >> 32) >= (unsigned)it)) break;
            }
            float d = __uint_as_float((unsigned)r1) +
                      __uint_as_float((unsigned)r2);
#pragma unroll
            for (int off = 1; off < 64; off <<= 1) d += __shfl_xor(d, off);
            if (lane == 0) sred4[w] = d;
        }
        __syncthreads();                                            // S1

        // ---- deferred convergence check of iteration `it` (barrier-free,
        //      uniform across threads and blocks)
        if (it >= 1) {
            float sd = sred4[0] + sred4[1];
            if (sd < THRESH) break;   // state: u_keep=u(it), v_keep, sv=v(it)
        }
        u_keep = u_new;

        // ---- post A(ep): staged values (8x 16B wave-store) + block pdiff
        if (t < NWB / 2) {
            u32x4 s;
            s.x = __float_as_uint(swave[2*t + 0]); s.y = ep;
            s.z = __float_as_uint(swave[2*t + 1]); s.w = ep;
            post16(&valA[b * NWB + 2*t], s);
        }
        if (t == 0) {
            float ps = 0.0f;
#pragma unroll
            for (int k = 0; k < NWB; ++k) ps += sdw[k];
            ASTORE(&rotR[(ep & 3) * NB + b],
                   ((u64)ep << 32) | __float_as_uint(ps));
        }
        // ---- poll A -> sv = u(ep)  (detection IS the fetch; one 16B load)
        {
            u32x4 q;
            for (;;) {
                q = poll16(&valA[2 * t]);
                if ((q.y >= ep) & (q.w >= ep)) break;
            }
            ((float2*)sv)[t] = make_float2(__uint_as_float(q.x),
                                           __uint_as_float(q.z));
        }
        __syncthreads();                                            // S2

        // ---- col compute: v(ep)_j from sv = u(ep)
        lds_row32(sv, lane, b32);
        lse = wave_lse(ccol, b32);
        float v_new = EPS * (LOG_AB - lse);
        float pdc   = fabsf(v_new - v_keep);
        v_keep = v_new;

        if (lane == 0) { swave[w] = v_new; sdw[w] = pdc; }
        __syncthreads();                                            // S3
        if (t < NWB / 2) {
            u32x4 s;
            s.x = __float_as_uint(swave[2*t + 0]); s.y = ep;
            s.z = __float_as_uint(swave[2*t + 1]); s.w = ep;
            post16(&valB[b * NWB + 2*t], s);
        }
        if (t == 0) {
            float ps = 0.0f;
#pragma unroll
            for (int k = 0; k < NWB; ++k) ps += sdw[k];
            ASTORE(&rotC[(ep & 3) * NB + b],
                   ((u64)ep << 32) | __float_as_uint(ps));
        }
        // ---- poll B -> sv = v(ep)
        {
            u32x4 q;
            for (;;) {
                q = poll16(&valB[2 * t]);
                if ((q.y >= ep) & (q.w >= ep)) break;
            }
            ((float2*)sv)[t] = make_float2(__uint_as_float(q.x),
                                           __uint_as_float(q.z));
        }
        __syncthreads();                                            // S4
    }

    // ---- epilogue: pi = exp((u_i + v_j - C_ij)/eps), cost = sum(pi*C)
    float cpart = 0.0f;
    {
        lds_row32(sv, lane, b32);          // sv = final v
        const float ui = u_keep;           // own row's final u (wave-uniform)
        float* orow = out + 1 + (size_t)i * NN;
#pragma unroll
        for (int k = 0; k < 8; ++k) {
#pragma unroll
            for (int kk = 0; kk < 4; ++kk) {
                float cc = crow[4*k+kk];
                float p  = __expf((ui + b32[4*k+kk] - cc) * INV_EPS);
                cpart = fmaf(p, cc, cpart);
                orow[4 * (lane + 64 * k) + kk] = p;  // crow in regs: alias-safe
            }
        }
    }
#pragma unroll
    for (int off = 1; off < 64; off <<= 1) cpart += __shfl_xor(cpart, off);
    if (lane == 0) sdw[w] = cpart;
    __syncthreads();
    if (t == 0) {
        float pc = 0.0f;
#pragma unroll
        for (int k = 0; k < NWB; ++k) pc += sdw[k];
        ASTORE(&costb[b], (1ull << 32) | __float_as_uint(pc));
    }
    if (b == 0) {                          // block 0 gathers the cost total
        if (t < NB) {
            u64 h;
            for (;;) { h = ALOAD(&costb[t]); if (h >= (1ull << 32)) break; }
            float pc = __uint_as_float((unsigned)h);
#pragma unroll
            for (int off = 1; off < 64; off <<= 1) pc += __shfl_xor(pc, off);
            if (lane == 0) sred4[w] = pc;
        }
        __syncthreads();
        if (t == 0) out[0] = sred4[0] + sred4[1];
    }
}

// ---------------------------------------------------------------------------
extern "C" void kernel_launch(void* const* d_in, const int* in_sizes, int n_in,
                              void* d_out, int out_size, void* d_ws, size_t ws_size,
                              hipStream_t stream)
{
    (void)in_sizes; (void)n_in; (void)out_size;
    const float* x = (const float*)d_in[0];
    const float* y = (const float*)d_in[1];
    float* out = (float*)d_out;
    char*  ws  = (char*)d_ws;

    const size_t CB = (size_t)NN * NN * sizeof(float);   // 16 MiB
    // signals: valA(2048) valB(2048) rotR(4*128) rotC(4*128) costb(128) u64
    const int    ZU = 2048 + 2048 + 512 + 512 + 128;     // 5248 u64
    const size_t ZB = (size_t)ZU * sizeof(u64);

    float *Cm, *CT; char* zz;
    int c_aligned, use_ct;
    if (ws_size >= 2 * CB + ZB) {             // preferred: C, CT, signals in ws
        Cm = (float*)ws; CT = (float*)(ws + CB); zz = ws + 2 * CB;
        c_aligned = 1; use_ct = 1;
    } else if (ws_size >= CB + ZB) {          // C in out+1, CT in ws
        Cm = out + 1; CT = (float*)ws; zz = ws + CB;
        c_aligned = 0; use_ct = 1;
    } else {                                  // C in out+1, no CT (strided)
        Cm = out + 1; CT = nullptr; zz = ws;
        c_aligned = 0; use_ct = 0;
    }
    u64* valA  = (u64*)zz;
    u64* valB  = valA + 2048;
    u64* rotR  = valB + 2048;
    u64* rotC  = rotR + 512;
    u64* costb = rotC + 512;
    int  zcount = ZU * 2;                     // u32 elements to zero

    hipLaunchKernelGGL(build_cost, dim3(32, 32), dim3(TPB_B), 0, stream,
                       x, y, Cm, CT, (unsigned*)zz, zcount, c_aligned, use_ct);

    const float* Cmc = Cm;
    const float* CTc = CT;
    void* args[] = { (void*)&Cmc, (void*)&CTc, (void*)&valA, (void*)&valB,
                     (void*)&rotR, (void*)&rotC, (void*)&costb,
                     (void*)&out, (void*)&c_aligned, (void*)&use_ct };
    hipLaunchCooperativeKernel((void*)sinkhorn_main, dim3(NB), dim3(TPB),
                               args, 0, stream);
}

// Round 7
// 663.426 us; speedup vs baseline: 1.1138x; 1.1118x over previous
//
#include <hip/hip_runtime.h>
#include <cstddef>

static constexpr int   NN      = 2048;
static constexpr int   TPB_B   = 256;   // build_cost block
static constexpr int   TPB     = 1024;  // main kernel block (16 waves)
static constexpr int   NWB     = TPB / 64;          // 16 waves/block
static constexpr int   NB      = 128;               // main grid blocks
static constexpr int   MAX_IT  = 100;
static constexpr float EPS     = 0.1f;
static constexpr float INV_EPS = 10.0f;
// logf(1/2048 + 1e-8)
static constexpr float LOG_AB  = -7.6245985063594f;
static constexpr float THRESH  = 0.1f;
// base-2 reformulation constants:
//   C1      = INV_EPS * log2(e)  (exp((b-c)/eps) == 2^((b-c)*C1))
//   EPS_LN2 = EPS * ln(2)        (eps * lse_ln == EPS_LN2 * lse_log2)
//   EPS_LAB = EPS * LOG_AB
static constexpr float C1      = 14.4269504088896340736f;
static constexpr float EPS_LN2 = 0.06931471805599453f;
static constexpr float EPS_LAB = -0.76245985063594f;

#define ALOAD(p)     __hip_atomic_load((p),  __ATOMIC_RELAXED, __HIP_MEMORY_SCOPE_AGENT)
#define ASTORE(p, x) __hip_atomic_store((p), (x), __ATOMIC_RELAXED, __HIP_MEMORY_SCOPE_AGENT)

typedef unsigned long long u64;
typedef unsigned int u32x4 __attribute__((ext_vector_type(4)));

// ---------------------------------------------------------------------------
// 16B coherent poll load: one transaction, load+wait+use in ONE asm block
// (R5 lesson: splitting load and waitcnt across asm blocks lets the compiler
// retarget registers -> poison reads that PASS the epoch check). sc0 sc1 =
// bypass the non-coherent per-XCD L2; reads/writes at the IC coherence
// point, same as agent-scope atomics. Layout: [val0][ep0][val1][ep1].
// ---------------------------------------------------------------------------
__device__ __forceinline__ u32x4 poll16(const u64* p)
{
    u32x4 q;
    asm volatile("global_load_dwordx4 %0, %1, off sc0 sc1\n\t"
                 "s_waitcnt vmcnt(0)"
                 : "=v"(q) : "v"(p) : "memory");
    return q;
}

__device__ __forceinline__ void post16(const u64* p, u32x4 s)
{
    asm volatile("global_store_dwordx4 %0, %1, off sc0 sc1"
                 :: "v"(p), "v"(s) : "memory");
}

// ---------------------------------------------------------------------------
// Fast math primitives (pure dataflow -> non-volatile asm, scheduler-free):
//   v_exp_f32 computes 2^x natively; __expf costs an extra v_mul (x*log2e).
//   v_log_f32 computes log2(x) natively; __logf adds a mul by ln2.
//   max3f: nested fmaxf fuses to v_max3_f32 (single VALU op, T17).
// Range note: exp2 args here are <= 0 and >= ~-2200 -> v_exp flushes to 0
// exactly like the previous __expf path (same post-scale magnitude).
// ---------------------------------------------------------------------------
__device__ __forceinline__ float exp2_fast(float x)
{
    float r;
    asm("v_exp_f32 %0, %1" : "=v"(r) : "v"(x));
    return r;
}
__device__ __forceinline__ float log2_fast(float x)
{
    float r;
    asm("v_log_f32 %0, %1" : "=v"(r) : "v"(x));
    return r;
}
__device__ __forceinline__ float max3f(float a, float b, float c)
{
    return fmaxf(fmaxf(a, b), c);
}

// ---------------------------------------------------------------------------
// Cost matrix build + signal-region zeroing. C[i][j] = sum_d (x[i,d]-y[j,d])^2.
// (harness poisons ws with 0xAA before every call -> re-zero signals every
//  launch; kernel-end L2 writeback makes plain stores visible to bypass loads)
// ---------------------------------------------------------------------------
__global__ __launch_bounds__(TPB_B)
void build_cost(const float* __restrict__ x, const float* __restrict__ y,
                float* __restrict__ C, float* __restrict__ CT,
                unsigned* __restrict__ zz, int zcount,
                int c_aligned, int use_ct)
{
    __shared__ float xs[64][65];
    __shared__ float ys[64][65];
    const int t  = threadIdx.x;
    const int bi = blockIdx.y, bj = blockIdx.x;

    if (bi == 0) {                       // 32 blocks zero the region in parallel
        int per = (zcount + 31) / 32;
        int lo = bj * per;
        int hi = lo + per; if (hi > zcount) hi = zcount;
        for (int idx = lo + t; idx < hi; idx += TPB_B) zz[idx] = 0u;
    }

#pragma unroll
    for (int k = 0; k < 16; ++k) {
        int idx = t + TPB_B * k;
        int r = idx >> 6, c = idx & 63;
        xs[r][c] = x[(size_t)(bi * 64 + r) * 64 + c];
        ys[r][c] = y[(size_t)(bj * 64 + r) * 64 + c];
    }
    __syncthreads();

    const int ti0 = (t >> 4) * 4;
    const int tj0 = (t & 15) * 4;
    float acc[4][4] = {};
#pragma unroll 8
    for (int d = 0; d < 64; ++d) {
        float xv[4], yv[4];
#pragma unroll
        for (int k = 0; k < 4; ++k) xv[k] = xs[ti0 + k][d];
#pragma unroll
        for (int l = 0; l < 4; ++l) yv[l] = ys[tj0 + l][d];
#pragma unroll
        for (int k = 0; k < 4; ++k)
#pragma unroll
            for (int l = 0; l < 4; ++l) {
                float df = xv[k] - yv[l];
                acc[k][l] = fmaf(df, df, acc[k][l]);
            }
    }

#pragma unroll
    for (int k = 0; k < 4; ++k) {
        size_t off = (size_t)(bi * 64 + ti0 + k) * NN + bj * 64 + tj0;
        if (c_aligned) {
            *(float4*)(C + off) = make_float4(acc[k][0], acc[k][1], acc[k][2], acc[k][3]);
        } else {
            C[off + 0] = acc[k][0]; C[off + 1] = acc[k][1];
            C[off + 2] = acc[k][2]; C[off + 3] = acc[k][3];
        }
    }
    if (use_ct) {
#pragma unroll
        for (int l = 0; l < 4; ++l) {
            size_t off = (size_t)(bj * 64 + tj0 + l) * NN + bi * 64 + ti0;
            *(float4*)(CT + off) = make_float4(acc[0][l], acc[1][l], acc[2][l], acc[3][l]);
        }
    }
}

// ---------------------------------------------------------------------------
// Helpers
// ---------------------------------------------------------------------------
__device__ __forceinline__ void load_row32(const float* row, int lane,
                                           int aligned, float c[32])
{
    if (aligned) {
        const float4* r4 = (const float4*)row;
#pragma unroll
        for (int k = 0; k < 8; ++k) {
            float4 A = r4[lane + 64 * k];
            c[4*k+0] = A.x; c[4*k+1] = A.y; c[4*k+2] = A.z; c[4*k+3] = A.w;
        }
    } else {
#pragma unroll
        for (int k = 0; k < 8; ++k) {
            const float* p = row + 4 * (lane + 64 * k);
            c[4*k+0] = p[0]; c[4*k+1] = p[1]; c[4*k+2] = p[2]; c[4*k+3] = p[3];
        }
    }
}

__device__ __forceinline__ void lds_row32(const float* sv, int lane, float b[32])
{
    const float4* s4 = (const float4*)sv;
#pragma unroll
    for (int k = 0; k < 8; ++k) {
        float4 A = s4[lane + 64 * k];
        b[4*k+0] = A.x; b[4*k+1] = A.y; b[4*k+2] = A.z; b[4*k+3] = A.w;
    }
}

// wave-level lse of (b-c)*INV_EPS over 2048 elems, IN LOG2 DOMAIN; result on
// ALL lanes. Returns lse_log2 = max2 + log2(sum 2^(t - max2)), t=(b-c)*C1.
// Caller converts: eps*(LOG_AB - lse_ln) == fmaf(-EPS_LN2, lse_log2, EPS_LAB).
// vs the ln-domain original: saves 32 v_mul (expf pre-scale), ~15 fmax (max3
// tree), 1 mul (logf post-scale) per call -> ~22% fewer VALU ops.
__device__ __forceinline__ float wave_lse2(const float c[32], const float b[32])
{
    // max over the 32 local diffs: max3 chain, 16 deep (b-c subs CSE with
    // the exp loop below)
    float M = fmaxf(b[0] - c[0], b[1] - c[1]);
#pragma unroll
    for (int k = 2; k < 32; k += 2)
        M = max3f(M, b[k] - c[k], b[k+1] - c[k+1]);
#pragma unroll
    for (int off = 1; off < 64; off <<= 1) M = fmaxf(M, __shfl_xor(M, off));
    const float M2 = M * C1;            // wave-uniform log2-domain max
    float s0 = 0.0f, s1 = 0.0f;
#pragma unroll
    for (int k = 0; k < 32; k += 2) {
        s0 += exp2_fast(fmaf(b[k]   - c[k],   C1, -M2));
        s1 += exp2_fast(fmaf(b[k+1] - c[k+1], C1, -M2));
    }
    float s = s0 + s1;
#pragma unroll
    for (int off = 1; off < 64; off <<= 1) s += __shfl_xor(s, off);
    return M2 + log2_fast(s);
}

// ---------------------------------------------------------------------------
// Main cooperative kernel — R6 (632us) structure UNCHANGED (4 barriers/iter,
// conv check folded into the staging barrier, staged coalesced 16B posts,
// self-validating {epoch|f32} entries, detection IS the fetch, no fences).
// ONE change: lse + exp math reformulated in log2 domain (wave_lse2 above,
// and the epilogue pi = 2^((u+v-C)*C1)) to use native v_exp/v_log without
// pre/post scaling muls. Analytically identical; rounding path differs
// (absmax headroom is ~6 orders of magnitude).
// Cm may alias out+1 (crow/ccol register-resident before any overwrite).
// ---------------------------------------------------------------------------
__global__ __launch_bounds__(TPB)
void sinkhorn_main(const float* Cm, const float* __restrict__ CT,
                   u64* __restrict__ valA, u64* __restrict__ valB,
                   u64* __restrict__ rotR, u64* __restrict__ rotC,
                   u64* __restrict__ costb,
                   float* out, int c_aligned, int use_ct)
{
    __shared__ float sv[2048];
    __shared__ float swave[NWB];
    __shared__ float sdw[NWB];
    __shared__ float sred4[4];
    const int t = threadIdx.x, lane = t & 63, w = t >> 6, b = blockIdx.x;
    const int i = b * NWB + w;

    // loop-invariant C row / CT col -> registers
    float crow[32], ccol[32];
    load_row32(Cm + (size_t)i * NN, lane, c_aligned, crow);
    if (use_ct) {
        load_row32(CT + (size_t)i * NN, lane, 1, ccol);
    } else {
#pragma unroll
        for (int k = 0; k < 8; ++k)
#pragma unroll
            for (int kk = 0; kk < 4; ++kk)
                ccol[4*k+kk] = Cm[(size_t)(4 * (lane + 64 * k) + kk) * NN + i];
    }

    for (int k = t; k < 2048; k += TPB) sv[k] = 0.0f;   // v(0) = 0
    __syncthreads();

    float u_keep = 0.0f, v_keep = 0.0f;
    float b32[32];

    for (int it = 0; it < MAX_IT; ++it) {
        const unsigned ep = (unsigned)(it + 1);

        // ---- row compute: u(ep)_i from sv = v(it)
        lds_row32(sv, lane, b32);
        float lse   = wave_lse2(crow, b32);
        float u_new = fmaf(-EPS_LN2, lse, EPS_LAB);  // eps*(LOG_AB - lse_ln)
        float pdr   = fabsf(u_new - u_keep);

        // ---- stage u(ep) + pdiff for the posts (read after S1)
        if (lane == 0) { swave[w] = u_new; sdw[w] = pdr; }

        // ---- conv inputs of iteration `it` (always-warm; posted >=2.5us
        //      ago) gathered by waves 0-1 while others head to S1
        if (it >= 1 && t < NB) {
            u64 r1, r2;
            const int ri = (it & 3) * NB + t;
            for (;;) {
                r1 = ALOAD(&rotR[ri]);
                r2 = ALOAD(&rotC[ri]);
                if (((unsigned)(r1 >> 32) >= (unsigned)it) &
                    ((unsigned)(r2 >> 32) >= (unsigned)it)) break;
            }
            float d = __uint_as_float((unsigned)r1) +
                      __uint_as_float((unsigned)r2);
#pragma unroll
            for (int off = 1; off < 64; off <<= 1) d += __shfl_xor(d, off);
            if (lane == 0) sred4[w] = d;
        }
        __syncthreads();                                            // S1

        // ---- deferred convergence check of iteration `it` (barrier-free,
        //      uniform across threads and blocks)
        if (it >= 1) {
            float sd = sred4[0] + sred4[1];
            if (sd < THRESH) break;   // state: u_keep=u(it), v_keep, sv=v(it)
        }
        u_keep = u_new;

        // ---- post A(ep): staged values (8x 16B wave-store) + block pdiff
        if (t < NWB / 2) {
            u32x4 s;
            s.x = __float_as_uint(swave[2*t + 0]); s.y = ep;
            s.z = __float_as_uint(swave[2*t + 1]); s.w = ep;
            post16(&valA[b * NWB + 2*t], s);
        }
        if (t == 0) {
            float ps = 0.0f;
#pragma unroll
            for (int k = 0; k < NWB; ++k) ps += sdw[k];
            ASTORE(&rotR[(ep & 3) * NB + b],
                   ((u64)ep << 32) | __float_as_uint(ps));
        }
        // ---- poll A -> sv = u(ep)  (detection IS the fetch; one 16B load)
        {
            u32x4 q;
            for (;;) {
                q = poll16(&valA[2 * t]);
                if ((q.y >= ep) & (q.w >= ep)) break;
            }
            ((float2*)sv)[t] = make_float2(__uint_as_float(q.x),
                                           __uint_as_float(q.z));
        }
        __syncthreads();                                            // S2

        // ---- col compute: v(ep)_j from sv = u(ep)
        lds_row32(sv, lane, b32);
        lse = wave_lse2(ccol, b32);
        float v_new = fmaf(-EPS_LN2, lse, EPS_LAB);
        float pdc   = fabsf(v_new - v_keep);
        v_keep = v_new;

        if (lane == 0) { swave[w] = v_new; sdw[w] = pdc; }
        __syncthreads();                                            // S3
        if (t < NWB / 2) {
            u32x4 s;
            s.x = __float_as_uint(swave[2*t + 0]); s.y = ep;
            s.z = __float_as_uint(swave[2*t + 1]); s.w = ep;
            post16(&valB[b * NWB + 2*t], s);
        }
        if (t == 0) {
            float ps = 0.0f;
#pragma unroll
            for (int k = 0; k < NWB; ++k) ps += sdw[k];
            ASTORE(&rotC[(ep & 3) * NB + b],
                   ((u64)ep << 32) | __float_as_uint(ps));
        }
        // ---- poll B -> sv = v(ep)
        {
            u32x4 q;
            for (;;) {
                q = poll16(&valB[2 * t]);
                if ((q.y >= ep) & (q.w >= ep)) break;
            }
            ((float2*)sv)[t] = make_float2(__uint_as_float(q.x),
                                           __uint_as_float(q.z));
        }
        __syncthreads();                                            // S4
    }

    // ---- epilogue: pi = 2^((u_i + v_j - C_ij)*C1), cost = sum(pi*C)
    float cpart = 0.0f;
    {
        lds_row32(sv, lane, b32);          // sv = final v
        const float uiC = u_keep * C1;     // own row's final u, log2-scaled
        float* orow = out + 1 + (size_t)i * NN;
#pragma unroll
        for (int k = 0; k < 8; ++k) {
#pragma unroll
            for (int kk = 0; kk < 4; ++kk) {
                float cc = crow[4*k+kk];
                float p  = exp2_fast(fmaf(b32[4*k+kk] - cc, C1, uiC));
                cpart = fmaf(p, cc, cpart);
                orow[4 * (lane + 64 * k) + kk] = p;  // crow in regs: alias-safe
            }
        }
    }
#pragma unroll
    for (int off = 1; off < 64; off <<= 1) cpart += __shfl_xor(cpart, off);
    if (lane == 0) sdw[w] = cpart;
    __syncthreads();
    if (t == 0) {
        float pc = 0.0f;
#pragma unroll
        for (int k = 0; k < NWB; ++k) pc += sdw[k];
        ASTORE(&costb[b], (1ull << 32) | __float_as_uint(pc));
    }
    if (b == 0) {                          // block 0 gathers the cost total
        if (t < NB) {
            u64 h;
            for (;;) { h = ALOAD(&costb[t]); if (h >= (1ull << 32)) break; }
            float pc = __uint_as_float((unsigned)h);
#pragma unroll
            for (int off = 1; off < 64; off <<= 1) pc += __shfl_xor(pc, off);
            if (lane == 0) sred4[w] = pc;
        }
        __syncthreads();
        if (t == 0) out[0] = sred4[0] + sred4[1];
    }
}

// ---------------------------------------------------------------------------
extern "C" void kernel_launch(void* const* d_in, const int* in_sizes, int n_in,
                              void* d_out, int out_size, void* d_ws, size_t ws_size,
                              hipStream_t stream)
{
    (void)in_sizes; (void)n_in; (void)out_size;
    const float* x = (const float*)d_in[0];
    const float* y = (const float*)d_in[1];
    float* out = (float*)d_out;
    char*  ws  = (char*)d_ws;

    const size_t CB = (size_t)NN * NN * sizeof(float);   // 16 MiB
    // signals: valA(2048) valB(2048) rotR(4*128) rotC(4*128) costb(128) u64
    const int    ZU = 2048 + 2048 + 512 + 512 + 128;     // 5248 u64
    const size_t ZB = (size_t)ZU * sizeof(u64);

    float *Cm, *CT; char* zz;
    int c_aligned, use_ct;
    if (ws_size >= 2 * CB + ZB) {             // preferred: C, CT, signals in ws
        Cm = (float*)ws; CT = (float*)(ws + CB); zz = ws + 2 * CB;
        c_aligned = 1; use_ct = 1;
    } else if (ws_size >= CB + ZB) {          // C in out+1, CT in ws
        Cm = out + 1; CT = (float*)ws; zz = ws + CB;
        c_aligned = 0; use_ct = 1;
    } else {                                  // C in out+1, no CT (strided)
        Cm = out + 1; CT = nullptr; zz = ws;
        c_aligned = 0; use_ct = 0;
    }
    u64* valA  = (u64*)zz;
    u64* valB  = valA + 2048;
    u64* rotR  = valB + 2048;
    u64* rotC  = rotR + 512;
    u64* costb = rotC + 512;
    int  zcount = ZU * 2;                     // u32 elements to zero

    hipLaunchKernelGGL(build_cost, dim3(32, 32), dim3(TPB_B), 0, stream,
                       x, y, Cm, CT, (unsigned*)zz, zcount, c_aligned, use_ct);

    const float* Cmc = Cm;
    const float* CTc = CT;
    void* args[] = { (void*)&Cmc, (void*)&CTc, (void*)&valA, (void*)&valB,
                     (void*)&rotR, (void*)&rotC, (void*)&costb,
                     (void*)&out, (void*)&c_aligned, (void*)&use_ct };
    hipLaunchCooperativeKernel((void*)sinkhorn_main, dim3(NB), dim3(TPB),
                               args, 0, stream);
}